// Round 5
// baseline (425.420 us; speedup 1.0000x reference)
//
#include <hip/hip_runtime.h>
#include <math.h>

#define BB 8
#define E  128
#define OO 256
#define HH 112
#define WW 112
#define HWP (HH*WW)   // 12544

typedef _Float16 f16;
typedef _Float16 half8 __attribute__((ext_vector_type(8)));
typedef float f32x4 __attribute__((ext_vector_type(4)));

// LDS octet swizzle (R4-verified: bank conflicts -> 0)
#define SWZ(q, c) ((((q) + ((c) >> 1)) & 3) * 8)

// ---------------- precompute 1: normalized f16 weights, layout [tap][o][ch]
__global__ __launch_bounds__(128)
void wnorm16_kernel(const float* __restrict__ wgt, f16* __restrict__ wn16) {
    int o = blockIdx.x;
    int c = threadIdx.x;
    const float* row = wgt + (size_t)o * 1152 + c * 9;
    float v[9];
    float ss = 0.f;
    #pragma unroll
    for (int tp = 0; tp < 9; ++tp) { v[tp] = row[tp]; ss = fmaf(v[tp], v[tp], ss); }
    ss += __shfl_xor(ss, 1);  ss += __shfl_xor(ss, 2);
    ss += __shfl_xor(ss, 4);  ss += __shfl_xor(ss, 8);
    ss += __shfl_xor(ss, 16); ss += __shfl_xor(ss, 32);
    __shared__ float r2[2];
    if ((c & 63) == 0) r2[c >> 6] = ss;
    __syncthreads();
    float inv = rsqrtf(fmaxf(r2[0] + r2[1], 1e-24f));
    #pragma unroll
    for (int tp = 0; tp < 9; ++tp)
        wn16[((size_t)tp * OO + o) * E + c] = (f16)(v[tp] * inv);
}

// ---------------- precompute 2: inverse patch norms pinv[b][h][w]
__global__ __launch_bounds__(256)
void pinv_kernel(const float* __restrict__ x, float* __restrict__ pinv) {
    int hp = blockIdx.x;   // 0..55
    int b  = blockIdx.y;   // 0..7
    int h0 = hp * 2;
    int t  = threadIdx.x;
    __shared__ float ssqR[4][114];   // rows h0-1..h0+2, cols -1..112 (offset +1)

    for (int i = t; i < 4 * 114; i += 256) {
        int r = i / 114, c = i % 114;
        int gh = h0 - 1 + r;
        int gw = c - 1;
        float s = 0.f;
        if ((unsigned)gh < HH && (unsigned)gw < WW) {
            const float* xp = x + ((size_t)b * E) * HWP + gh * WW + gw;
            #pragma unroll 8
            for (int ch = 0; ch < E; ++ch) {
                float v = xp[(size_t)ch * HWP];
                s = fmaf(v, v, s);
            }
        }
        ssqR[r][c] = s;
    }
    __syncthreads();
    if (t < 224) {
        int dh = t / 112, w = t % 112;
        float S = 0.f;
        #pragma unroll
        for (int r = 0; r < 3; ++r)
            #pragma unroll
            for (int c = 0; c < 3; ++c)
                S += ssqR[dh + r][w + c];
        pinv[(size_t)b * HWP + (h0 + dh) * WW + w] = rsqrtf(fmaxf(S, 1e-24f));
    }
}

// ---------------- tier-1 main: pipelined MFMA kernel (no norm bookkeeping)
// Block: 64 o x 2 h x 128 w; 4 waves; wave = 64o x 64px (m4 x n4, 16x16x32 f16).
// Pipeline: L0 W0 | L1 M0 | W1 | L2 M1 | W2 | L3 M2 | W3 | M3  (single LDS buf)
__global__ __launch_bounds__(256, 2)
void cossim_pipe(const float* __restrict__ x, const f16* __restrict__ wn16,
                 const float* __restrict__ pinv, float* __restrict__ out) {
    int hp = blockIdx.x;
    int oy = blockIdx.y;
    int b  = blockIdx.z;
    int h0 = hp * 2;
    int o0 = oy * 64;
    int t    = threadIdx.x;
    int lane = t & 63;
    int wv   = t >> 6;

    __shared__ f16 ws[9][64][32];
    __shared__ f16 xs[4][130][32];

    f32x4 zero4 = {0.f, 0.f, 0.f, 0.f};
    f32x4 acc[4][4];
    #pragma unroll
    for (int mi = 0; mi < 4; ++mi)
        #pragma unroll
        for (int ni = 0; ni < 4; ++ni) acc[mi][ni] = zero4;

    const int lr = lane & 15;
    const int ls = lane >> 4;

    // staging roles
    const int wo = t >> 2, wq = t & 3;            // weights: o, octet
    const int colL = lane & 15, cq = lane >> 4;   // x: col sub-lane, c-octet

    // pipeline registers (single set; lifetimes alternate L_c..W_c)
    float vv[9][8];
    half8 wreg[9];

#define LOADW(CH0)                                                              \
    {                                                                           \
        _Pragma("unroll")                                                       \
        for (int r = 0; r < 9; ++r)                                             \
            wreg[r] = *(const half8*)(wn16 +                                    \
                ((size_t)(r * OO + o0 + wo)) * E + (CH0) + wq * 8);             \
    }

#define LOADX(CH0)                                                              \
    {                                                                           \
        _Pragma("unroll")                                                       \
        for (int it = 0; it < 9; ++it) {                                        \
            int g = it * 4 + wv;                                                \
            int r = g / 9, colb = g % 9;                                        \
            int cs = colb * 16 + colL;                                          \
            int gh = h0 - 1 + r;                                                \
            int gw = cs - 1;                                                    \
            bool ok = (cs < 130) && ((unsigned)gh < HH) && ((unsigned)gw < WW); \
            const float* xp = x + ((size_t)b * E + (CH0) + cq * 8) * HWP        \
                              + gh * WW + gw;                                   \
            _Pragma("unroll")                                                   \
            for (int e = 0; e < 8; ++e)                                         \
                vv[it][e] = ok ? xp[e * HWP] : 0.f;                             \
        }                                                                       \
    }

#define WRITE()                                                                 \
    {                                                                           \
        _Pragma("unroll")                                                       \
        for (int r = 0; r < 9; ++r)                                             \
            *(half8*)&ws[r][wo][SWZ(wq, wo)] = wreg[r];                         \
        _Pragma("unroll")                                                       \
        for (int it = 0; it < 9; ++it) {                                        \
            int g = it * 4 + wv;                                                \
            int r = g / 9, colb = g % 9;                                        \
            int cs = colb * 16 + colL;                                          \
            if (cs < 130) {                                                     \
                half8 pk;                                                       \
                _Pragma("unroll")                                               \
                for (int e = 0; e < 8; ++e) pk[e] = (f16)vv[it][e];             \
                *(half8*)&xs[r][cs][SWZ(cq, cs)] = pk;                          \
            }                                                                   \
        }                                                                       \
    }

#define MFMA()                                                                  \
    {                                                                           \
        __builtin_amdgcn_s_setprio(1);                                          \
        _Pragma("unroll")                                                       \
        for (int tap = 0; tap < 9; ++tap) {                                     \
            int kh = tap / 3, kw = tap % 3;                                     \
            half8 A[4], Bf[4];                                                  \
            _Pragma("unroll")                                                   \
            for (int mi = 0; mi < 4; ++mi) {                                    \
                int row = mi * 16 + lr;                                         \
                A[mi] = *(const half8*)&ws[tap][row][SWZ(ls, row)];             \
            }                                                                   \
            _Pragma("unroll")                                                   \
            for (int dh = 0; dh < 2; ++dh)                                      \
                _Pragma("unroll")                                               \
                for (int wsg = 0; wsg < 2; ++wsg) {                             \
                    int col = wv * 32 + wsg * 16 + lr + kw;                     \
                    Bf[dh*2 + wsg] =                                            \
                        *(const half8*)&xs[dh + kh][col][SWZ(ls, col)];         \
                }                                                               \
            _Pragma("unroll")                                                   \
            for (int mi = 0; mi < 4; ++mi)                                      \
                _Pragma("unroll")                                               \
                for (int ni = 0; ni < 4; ++ni)                                  \
                    acc[mi][ni] = __builtin_amdgcn_mfma_f32_16x16x32_f16(       \
                        A[mi], Bf[ni], acc[mi][ni], 0, 0, 0);                   \
        }                                                                       \
        __builtin_amdgcn_s_setprio(0);                                          \
    }

    LOADW(0); LOADX(0);
    WRITE();
    __syncthreads();
    LOADW(32); LOADX(32);
    MFMA();
    __syncthreads();
    WRITE();
    __syncthreads();
    LOADW(64); LOADX(64);
    MFMA();
    __syncthreads();
    WRITE();
    __syncthreads();
    LOADW(96); LOADX(96);
    MFMA();
    __syncthreads();
    WRITE();
    __syncthreads();
    MFMA();

#undef LOADW
#undef LOADX
#undef WRITE
#undef MFMA

    // epilogue: scale by pinv only (weights pre-normalized)
    int lq = lane >> 4;
    #pragma unroll
    for (int ni = 0; ni < 4; ++ni) {
        int dh = ni >> 1, wsg = ni & 1;
        int w = wv * 32 + wsg * 16 + lr;
        if (w >= WW) continue;
        float pv = pinv[(size_t)b * HWP + (h0 + dh) * WW + w];
        int h = h0 + dh;
        #pragma unroll
        for (int mi = 0; mi < 4; ++mi) {
            #pragma unroll
            for (int rg = 0; rg < 4; ++rg) {
                int row = lq * 4 + rg;
                out[((size_t)(b * OO + o0 + mi*16 + row)) * HWP + h * WW + w]
                    = acc[mi][ni][rg] * pv;
            }
        }
    }
}

// ---------------- fallback (R4-proven) main kernel
template<int FAST>
__global__ __launch_bounds__(256, 2)
void cossim_mfma(const float* __restrict__ x, const float* __restrict__ wgt,
                 const f16* __restrict__ wn16, float* __restrict__ out) {
    int hp = blockIdx.x;
    int oy = blockIdx.y;
    int b  = blockIdx.z;
    int h0 = hp * 2;
    int o0 = oy * 64;
    int t    = threadIdx.x;
    int lane = t & 63;
    int wv   = t >> 6;

    __shared__ f16   ws[9][64][32];
    __shared__ f16   xs[4][130][32];
    __shared__ float ssqAcc[4][130];
    __shared__ float wSsq[64];
    __shared__ float pinvL[2][128];
    __shared__ float winv[64];

    for (int i = t; i < 4*130 + 64; i += 256) {
        if (i < 4*130) ((float*)ssqAcc)[i] = 0.f;
        else wSsq[i - 4*130] = 0.f;
    }
    __syncthreads();

    f32x4 zero4 = {0.f, 0.f, 0.f, 0.f};
    f32x4 acc[4][4];
    #pragma unroll
    for (int mi = 0; mi < 4; ++mi)
        #pragma unroll
        for (int ni = 0; ni < 4; ++ni) acc[mi][ni] = zero4;

    const int lr = lane & 15;
    const int ls = lane >> 4;

    for (int ch0 = 0; ch0 < E; ch0 += 32) {
        if (FAST) {
            int o = t >> 2, q = t & 3;
            #pragma unroll
            for (int r = 0; r < 9; ++r) {
                half8 v = *(const half8*)(wn16 + ((size_t)(r * OO + o0 + o)) * E + ch0 + q * 8);
                *(half8*)&ws[r][o][SWZ(q, o)] = v;
            }
        } else {
            int o = t >> 2, q = t & 3;
            const float* wrow = wgt + (size_t)(o0 + o) * 1152 + ch0 * 9 + q * 72;
            float v[72];
            float ss = 0.f;
            #pragma unroll
            for (int i = 0; i < 18; ++i) {
                float4 f = ((const float4*)wrow)[i];
                v[i*4+0] = f.x; v[i*4+1] = f.y; v[i*4+2] = f.z; v[i*4+3] = f.w;
                ss = fmaf(f.x, f.x, ss); ss = fmaf(f.y, f.y, ss);
                ss = fmaf(f.z, f.z, ss); ss = fmaf(f.w, f.w, ss);
            }
            #pragma unroll
            for (int tp = 0; tp < 9; ++tp) {
                half8 pk;
                #pragma unroll
                for (int cl = 0; cl < 8; ++cl) pk[cl] = (f16)v[cl*9 + tp];
                *(half8*)&ws[tp][o][SWZ(q, o)] = pk;
            }
            ss += __shfl_xor(ss, 1);
            ss += __shfl_xor(ss, 2);
            if (q == 0) wSsq[o] += ss;
        }
        {
            int colL = lane & 15, cq = lane >> 4;
            #pragma unroll 2
            for (int it = 0; it < 9; ++it) {
                int g = it * 4 + wv;
                int r = g / 9, colb = g % 9;
                int cs = colb * 16 + colL;
                int gh = h0 - 1 + r;
                int gw = cs - 1;
                bool okc = (cs < 130);
                bool ok  = okc && ((unsigned)gh < HH) && ((unsigned)gw < WW);
                const float* xp = x + ((size_t)b * E + ch0 + cq * 8) * HWP + gh * WW + gw;
                float vv[8];
                float ss = 0.f;
                #pragma unroll
                for (int e = 0; e < 8; ++e) {
                    float v = ok ? xp[e * HWP] : 0.f;
                    vv[e] = v;
                    ss = fmaf(v, v, ss);
                }
                if (okc) {
                    half8 pk;
                    #pragma unroll
                    for (int e = 0; e < 8; ++e) pk[e] = (f16)vv[e];
                    *(half8*)&xs[r][cs][SWZ(cq, cs)] = pk;
                }
                ss += __shfl_xor(ss, 16);
                ss += __shfl_xor(ss, 32);
                if (cq == 0 && okc) ssqAcc[r][cs] += ss;
            }
        }
        __syncthreads();

        __builtin_amdgcn_s_setprio(1);
        #pragma unroll
        for (int tap = 0; tap < 9; ++tap) {
            int kh = tap / 3, kw = tap % 3;
            half8 A[4], Bf[4];
            #pragma unroll
            for (int mi = 0; mi < 4; ++mi) {
                int row = mi * 16 + lr;
                A[mi] = *(const half8*)&ws[tap][row][SWZ(ls, row)];
            }
            #pragma unroll
            for (int dh = 0; dh < 2; ++dh)
                #pragma unroll
                for (int wsg = 0; wsg < 2; ++wsg) {
                    int col = wv * 32 + wsg * 16 + lr + kw;
                    Bf[dh*2 + wsg] = *(const half8*)&xs[dh + kh][col][SWZ(ls, col)];
                }
            #pragma unroll
            for (int mi = 0; mi < 4; ++mi)
                #pragma unroll
                for (int ni = 0; ni < 4; ++ni)
                    acc[mi][ni] = __builtin_amdgcn_mfma_f32_16x16x32_f16(
                        A[mi], Bf[ni], acc[mi][ni], 0, 0, 0);
        }
        __builtin_amdgcn_s_setprio(0);
        __syncthreads();
    }

    if (!FAST && t < 64) winv[t] = rsqrtf(fmaxf(wSsq[t], 1e-24f));
    {
        int dh = t >> 7, w = t & 127;
        float S = 0.f;
        #pragma unroll
        for (int r = 0; r < 3; ++r)
            #pragma unroll
            for (int c = 0; c < 3; ++c)
                S += ssqAcc[dh + r][w + c];
        pinvL[dh][w] = rsqrtf(fmaxf(S, 1e-24f));
    }
    __syncthreads();

    int lq = lane >> 4;
    #pragma unroll
    for (int ni = 0; ni < 4; ++ni) {
        int dh = ni >> 1, wsg = ni & 1;
        int w = wv * 32 + wsg * 16 + lr;
        if (w >= WW) continue;
        float pv = pinvL[dh][w];
        int h = h0 + dh;
        #pragma unroll
        for (int mi = 0; mi < 4; ++mi) {
            #pragma unroll
            for (int rg = 0; rg < 4; ++rg) {
                int row = lq * 4 + rg;
                float s = acc[mi][ni][rg] * pv;
                if (!FAST) s *= winv[mi*16 + row];
                out[((size_t)(b * OO + o0 + mi*16 + row)) * HWP + h * WW + w] = s;
            }
        }
    }
}

extern "C" void kernel_launch(void* const* d_in, const int* in_sizes, int n_in,
                              void* d_out, int out_size, void* d_ws, size_t ws_size,
                              hipStream_t stream) {
    const float* x   = (const float*)d_in[0];
    const float* wgt = (const float*)d_in[1];
    float* out = (float*)d_out;

    const size_t pinv_bytes = (size_t)BB * HWP * sizeof(float);      // 401408
    const size_t wn_bytes   = (size_t)9 * OO * E * sizeof(f16);      // 589824
    if (ws_size >= pinv_bytes + wn_bytes && d_ws != nullptr) {
        float* pinv = (float*)d_ws;
        f16*   wn16 = (f16*)((char*)d_ws + pinv_bytes);
        wnorm16_kernel<<<OO, 128, 0, stream>>>(wgt, wn16);
        pinv_kernel<<<dim3(56, BB), 256, 0, stream>>>(x, pinv);
        cossim_pipe<<<dim3(56, 4, BB), 256, 0, stream>>>(x, wn16, pinv, out);
    } else if (ws_size >= wn_bytes && d_ws != nullptr) {
        f16* wn16 = (f16*)d_ws;
        wnorm16_kernel<<<OO, 128, 0, stream>>>(wgt, wn16);
        cossim_mfma<1><<<dim3(56, 4, BB), 256, 0, stream>>>(x, wgt, wn16, out);
    } else {
        cossim_mfma<0><<<dim3(56, 4, BB), 256, 0, stream>>>(x, wgt, nullptr, out);
    }
}